// Round 5
// baseline (72.069 us; speedup 1.0000x reference)
//
#include <hip/hip_runtime.h>
#include <math.h>

#define HWDIM 96
#define NPIX (HWDIM*HWDIM)     // 9216
#define BATCH 2
#define CIN 64
#define CCAT 128
#define PADW 98                // 96 + 2 halo

typedef __attribute__((ext_vector_type(8))) short bf16x8;
typedef __attribute__((ext_vector_type(4))) float f32x4;

__device__ __forceinline__ unsigned short f2bf(float f) {
    unsigned u = __builtin_bit_cast(unsigned, f);
    unsigned r = (u + 0x7FFFu + ((u >> 16) & 1u)) >> 16;
    return (unsigned short)r;
}

// ---------------------------------------------------------------------------
// Kernel A: prep = pad (blocks 0..195) + weight transpose (blocks 196..231)
// ---------------------------------------------------------------------------
__global__ __launch_bounds__(256) void prep_kernel(
        const float* __restrict__ x,
        const float* __restrict__ wq, const float* __restrict__ wk,
        const float* __restrict__ wv,
        unsigned short* __restrict__ xp, unsigned short* __restrict__ wbT) {
    int bid = blockIdx.x;
    int tid = threadIdx.x;
    if (bid < BATCH * PADW) {
        __shared__ float xls[64][97];
        int b  = bid / PADW;
        int hp = bid % PADW;
        bool interior = (hp >= 1 && hp <= HWDIM);
        if (interior) {
            int h = hp - 1;
            for (int idx = tid; idx < 64 * HWDIM; idx += 256) {
                int ci = idx / HWDIM;
                int w  = idx % HWDIM;
                xls[ci][w] = x[((b * CIN + ci) * HWDIM + h) * HWDIM + w];
            }
        }
        __syncthreads();
        for (int idx = tid; idx < PADW * 64; idx += 256) {
            int wp = idx / 64;
            int ci = idx % 64;
            float v = 0.f;
            if (interior && wp >= 1 && wp <= HWDIM) v = xls[ci][wp - 1];
            xp[((b * PADW + hp) * PADW + wp) * 64 + ci] = f2bf(v);
        }
    } else {
        int base = (bid - BATCH * PADW) * 4096;
        #pragma unroll
        for (int e = 0; e < 16; ++e) {
            int idx = base + e * 256 + tid;      // < 147456
            int t   = idx / (256 * 64);
            int rem = idx % (256 * 64);
            int co  = rem / 64;
            int ci  = rem % 64;
            float val;
            if (co < 64)        val = wq[(co * 64 + ci) * 9 + t];
            else if (co < 128)  val = wk[((co - 64) * 64 + ci) * 9 + t];
            else                val = wv[((co - 128) * 64 + ci) * 9 + t];
            wbT[(t * 256 + co) * 64 + ci] = f2bf(val);
        }
    }
}

// ---------------------------------------------------------------------------
// Kernel B: conv, tap-decomposed implicit GEMM, bf16 MFMA 16x16x32.
// grid = (384, 2): x -> (b, h, half-row of 48); y -> co chunk of 128.
// Block stages 3 padded rows x 50 px in LDS (21.6 KB). 4 waves, each M48 x N32.
// y==0 blocks also write the positional encoding (ch 64..127 of Qb, Kb).
// ---------------------------------------------------------------------------
__global__ __launch_bounds__(256) void conv_mfma(
        const unsigned short* __restrict__ xp,
        const unsigned short* __restrict__ wbT,
        const float* __restrict__ bq, const float* __restrict__ bk,
        const float* __restrict__ bv,
        unsigned short* __restrict__ Qb, unsigned short* __restrict__ Kb,
        unsigned short* __restrict__ Vb) {
    __shared__ unsigned short xs[3 * 50 * 72];   // 21600 B
    int bx   = blockIdx.x;
    int b    = bx / 192;
    int hh   = bx % 192;
    int h    = hh >> 1;
    int w0   = (hh & 1) * 48;
    int co0  = blockIdx.y * 128;
    int tid  = threadIdx.x;

    // stage 3 padded rows x 50 px x 64 ch (1200 16B chunks)
    for (int i = tid; i < 1200; i += 256) {
        int r    = i / 400;
        int rem  = i % 400;
        int wp50 = rem >> 3;
        int c8   = rem & 7;
        const uint4* src = (const uint4*)&xp[(((b * PADW) + h + r) * PADW + w0 + wp50) * 64 + c8 * 8];
        *(uint4*)&xs[(r * 50 + wp50) * 72 + c8 * 8] = *src;
    }
    __syncthreads();

    int lane = tid & 63;
    int wv   = tid >> 6;
    int lw   = lane & 15;
    int ksub = (lane >> 4) * 8;
    int co_t = co0 + wv * 32;

    f32x4 acc[3][2];
    #pragma unroll
    for (int m = 0; m < 3; ++m)
        #pragma unroll
        for (int n = 0; n < 2; ++n) acc[m][n] = (f32x4){0.f, 0.f, 0.f, 0.f};

    #pragma unroll
    for (int t = 0; t < 9; ++t) {
        int kh = t / 3, kw = t % 3;
        #pragma unroll
        for (int half = 0; half < 2; ++half) {
            const unsigned short* ap = xs + (kh * 50 + lw + kw) * 72 + half * 32 + ksub;
            bf16x8 A0 = *(const bf16x8*)(ap);
            bf16x8 A1 = *(const bf16x8*)(ap + 16 * 72);
            bf16x8 A2 = *(const bf16x8*)(ap + 32 * 72);
            const unsigned short* bp = wbT + ((t * 256 + co_t + lw) * 64) + half * 32 + ksub;
            bf16x8 B0 = *(const bf16x8*)(bp);
            bf16x8 B1 = *(const bf16x8*)(bp + 16 * 64);
            acc[0][0] = __builtin_amdgcn_mfma_f32_16x16x32_bf16(A0, B0, acc[0][0], 0, 0, 0);
            acc[0][1] = __builtin_amdgcn_mfma_f32_16x16x32_bf16(A0, B1, acc[0][1], 0, 0, 0);
            acc[1][0] = __builtin_amdgcn_mfma_f32_16x16x32_bf16(A1, B0, acc[1][0], 0, 0, 0);
            acc[1][1] = __builtin_amdgcn_mfma_f32_16x16x32_bf16(A1, B1, acc[1][1], 0, 0, 0);
            acc[2][0] = __builtin_amdgcn_mfma_f32_16x16x32_bf16(A2, B0, acc[2][0], 0, 0, 0);
            acc[2][1] = __builtin_amdgcn_mfma_f32_16x16x32_bf16(A2, B1, acc[2][1], 0, 0, 0);
        }
    }

    #pragma unroll
    for (int n = 0; n < 2; ++n) {
        int cg   = co_t + n * 16;
        int co_f = cg + lw;
        #pragma unroll
        for (int m = 0; m < 3; ++m) {
            int wb = w0 + m * 16 + ((lane >> 4) << 2);
            if (cg < 64) {
                float bval = bq[co_f];
                #pragma unroll
                for (int r = 0; r < 4; ++r) {
                    int pix = b * NPIX + h * HWDIM + wb + r;
                    Qb[pix * CCAT + co_f] = f2bf(acc[m][n][r] + bval);
                }
            } else if (cg < 128) {
                int ch = co_f - 64;
                float bval = bk[ch];
                #pragma unroll
                for (int r = 0; r < 4; ++r) {
                    int pix = b * NPIX + h * HWDIM + wb + r;
                    Kb[pix * CCAT + ch] = f2bf(acc[m][n][r] + bval);
                }
            } else {
                int ch = co_f - 128;
                float bval = bv[ch];
                #pragma unroll
                for (int r = 0; r < 4; ++r) {
                    int pix = b * NPIX + h * HWDIM + wb + r;
                    Vb[pix * CCAT + ch] = f2bf(acc[m][n][r] + bval);
                }
            }
        }
    }

    // positional encoding (ch 64..127 of Qb and Kb) by y==0 blocks
    if (blockIdx.y == 0) {
        for (int i = tid; i < 48 * 64; i += 256) {
            int c  = i & 63;
            int pl = i >> 6;
            int w  = w0 + pl;
            int pos = (c < 32) ? h : w;
            int j   = c & 15;
            float f   = exp2f(-(float)j * 0.83048202372184059f);
            float ang = (float)pos * f;
            float val = ((c & 16) == 0) ? sinf(ang) : cosf(ang);
            unsigned short bvv = f2bf(val);
            int pix = b * NPIX + h * HWDIM + w;
            Qb[pix * CCAT + 64 + c] = bvv;
            Kb[pix * CCAT + 64 + c] = bvv;
        }
    }
}

// ---------------------------------------------------------------------------
// Kernel C: neighborhood attention, fully MFMA (QK^T and PV).
// Block = 4x4 same-parity query tile; key union 10x10.
// QK^T: M16 x N112 x K128ch. Softmax -> Pb bf16 [16q][128nbr].
// PV: M16(q) x N128(ch) x K128(nbr) with V transposed in LDS.
// ---------------------------------------------------------------------------
#define KPAD 136   // bf16 row pad (272 B, 16B-aligned)
#define LGP  114   // f32 logit row stride; MUST be >= 112 (QK^T writes cols 0..111)

__global__ __launch_bounds__(256) void natt_mfma(
        const unsigned short* __restrict__ Qb,
        const unsigned short* __restrict__ Kb,
        const unsigned short* __restrict__ Vb,
        float* __restrict__ out) {
    __shared__ unsigned short Ks[112 * KPAD];   // 30464 B
    __shared__ unsigned short Vt[128 * KPAD];   // 34816 B  Vt[ch][nbr]
    __shared__ unsigned short Qs[16 * KPAD];    //  4352 B
    __shared__ unsigned short Pb[16 * KPAD];    //  4352 B  Pb[q][nbr]
    __shared__ float Lg[16 * LGP];              //  7296 B

    int bid = blockIdx.x;
    int tw = bid % 12;
    int th = (bid / 12) % 12;
    int gw = (bid / 144) & 1;
    int gh = (bid / 288) & 1;
    int b  = bid / 576;
    int rh0 = th * 4, rw0 = tw * 4;
    int base_h = min(max(rh0 - 3, 0), 41);
    int base_w = min(max(rw0 - 3, 0), 41);
    int tid = threadIdx.x;

    // zero-fill Vt cols 100..127 (avoid garbage x nonzero in PV MFMA)
    if (tid < 128) {
        unsigned short* row = Vt + tid * KPAD;
        *(unsigned long long*)(row + 100) = 0ull;
        *(uint4*)(row + 104) = (uint4){0, 0, 0, 0};
        *(uint4*)(row + 112) = (uint4){0, 0, 0, 0};
        *(uint4*)(row + 120) = (uint4){0, 0, 0, 0};
    }

    // stage K (row-major), V (transposed scatter), Q
    for (int c = tid; c < 3456; c += 256) {
        if (c < 3200) {
            int isV = c >= 1600;
            int cc  = isV ? c - 1600 : c;
            int px  = cc >> 4, c8 = cc & 15;
            int ih  = px / 10, iw = px - ih * 10;
            int nh  = gh + 2 * min(base_h + ih, 47);
            int nw2 = gw + 2 * min(base_w + iw, 47);
            int gp  = b * NPIX + nh * HWDIM + nw2;
            uint4 v = *(const uint4*)((isV ? Vb : Kb) + gp * CCAT + c8 * 8);
            if (!isV) {
                *(uint4*)(Ks + px * KPAD + c8 * 8) = v;
            } else {
                const unsigned short* e = (const unsigned short*)&v;
                #pragma unroll
                for (int jj = 0; jj < 8; ++jj) {
                    int j = (jj + tid) & 7;              // bank swizzle
                    Vt[(c8 * 8 + j) * KPAD + px] = e[j];
                }
            }
        } else {
            int cc = c - 3200;
            int q  = cc >> 4, c8 = cc & 15;
            int qi = q >> 2, qj = q & 3;
            int hh = gh + 2 * (rh0 + qi);
            int ww = gw + 2 * (rw0 + qj);
            int gp = b * NPIX + hh * HWDIM + ww;
            uint4 v = *(const uint4*)(Qb + gp * CCAT + c8 * 8);
            *(uint4*)(Qs + q * KPAD + c8 * 8) = v;
        }
    }
    __syncthreads();

    // ---- QK^T MFMA ----
    int lane = tid & 63;
    int wv   = tid >> 6;
    int lw   = lane & 15;
    int ks8  = (lane >> 4) * 8;
    const float scale = 0.08838834764831845f;

    #pragma unroll
    for (int tt = 0; tt < 2; ++tt) {
        int tile = wv + tt * 4;
        if (tile < 7) {
            f32x4 acc = (f32x4){0.f, 0.f, 0.f, 0.f};
            #pragma unroll
            for (int kk = 0; kk < 4; ++kk) {
                bf16x8 A  = *(const bf16x8*)(Qs + lw * KPAD + kk * 32 + ks8);
                bf16x8 Bf = *(const bf16x8*)(Ks + (tile * 16 + lw) * KPAD + kk * 32 + ks8);
                acc = __builtin_amdgcn_mfma_f32_16x16x32_bf16(A, Bf, acc, 0, 0, 0);
            }
            #pragma unroll
            for (int r = 0; r < 4; ++r) {
                int m = (lane >> 4) * 4 + r;
                Lg[m * LGP + tile * 16 + lw] = acc[r] * scale;
            }
        }
    }
    __syncthreads();

    // ---- softmax (16 threads per query) -> Pb bf16 ----
    int q   = tid >> 4, k16 = tid & 15;
    {
        int qi  = q >> 2, qj = q & 3;
        int rh  = rh0 + qi, rw = rw0 + qj;
        int oh  = min(max(rh - 3, 0), 41) - base_h;
        int ow  = min(max(rw - 3, 0), 41) - base_w;

        float ev[4];
        int   en[4];
        float mx = -1e30f;
        #pragma unroll
        for (int u = 0; u < 4; ++u) {
            int idx = k16 + u * 16;
            if (idx < 49) {
                int i = idx / 7, j = idx - i * 7;
                int n = (oh + i) * 10 + ow + j;
                en[u] = n;
                float l = Lg[q * LGP + n];
                ev[u] = l;
                mx = fmaxf(mx, l);
            } else { en[u] = -1; ev[u] = 0.f; }
        }
        #pragma unroll
        for (int off = 8; off > 0; off >>= 1) mx = fmaxf(mx, __shfl_xor(mx, off));
        float s = 0.f;
        #pragma unroll
        for (int u = 0; u < 4; ++u)
            if (en[u] >= 0) { ev[u] = __expf(ev[u] - mx); s += ev[u]; }
        #pragma unroll
        for (int off = 8; off > 0; off >>= 1) s += __shfl_xor(s, off);
        float rs = 1.0f / s;
        // zero own 8-col slice, then scatter valid p (same wave: ordered)
        *(uint4*)(Pb + q * KPAD + k16 * 8) = (uint4){0, 0, 0, 0};
        #pragma unroll
        for (int u = 0; u < 4; ++u)
            if (en[u] >= 0) Pb[q * KPAD + en[u]] = f2bf(ev[u] * rs);
    }
    __syncthreads();

    // ---- PV MFMA: wave handles ch-tiles 2wv, 2wv+1 ----
    bf16x8 A4[4];
    #pragma unroll
    for (int kk = 0; kk < 4; ++kk)
        A4[kk] = *(const bf16x8*)(Pb + lw * KPAD + kk * 32 + ks8);

    #pragma unroll
    for (int tt = 0; tt < 2; ++tt) {
        int tile = wv * 2 + tt;
        f32x4 acc = (f32x4){0.f, 0.f, 0.f, 0.f};
        #pragma unroll
        for (int kk = 0; kk < 4; ++kk) {
            bf16x8 Bf = *(const bf16x8*)(Vt + (tile * 16 + lw) * KPAD + kk * 32 + ks8);
            acc = __builtin_amdgcn_mfma_f32_16x16x32_bf16(A4[kk], Bf, acc, 0, 0, 0);
        }
        int ch = tile * 16 + lw;
        #pragma unroll
        for (int r = 0; r < 4; ++r) {
            int qq = (lane >> 4) * 4 + r;
            int qi = qq >> 2, qj = qq & 3;
            int gp = b * NPIX + (gh + 2 * (rh0 + qi)) * HWDIM + (gw + 2 * (rw0 + qj));
            out[gp * CCAT + ch] = acc[r];
        }
    }
}

// ---------------------------------------------------------------------------
extern "C" void kernel_launch(void* const* d_in, const int* in_sizes, int n_in,
                              void* d_out, int out_size, void* d_ws, size_t ws_size,
                              hipStream_t stream) {
    const float* x  = (const float*)d_in[0];
    const float* wq = (const float*)d_in[1];
    const float* bq = (const float*)d_in[2];
    const float* wk = (const float*)d_in[3];
    const float* bk = (const float*)d_in[4];
    const float* wv = (const float*)d_in[5];
    const float* bv = (const float*)d_in[6];

    unsigned short* ws = (unsigned short*)d_ws;
    unsigned short* Qb  = ws;                              // 2359296 bf16
    unsigned short* Kb  = Qb + BATCH * NPIX * CCAT;
    unsigned short* Vb  = Kb + BATCH * NPIX * CCAT;
    unsigned short* xp  = Vb + BATCH * NPIX * CCAT;        // 2*98*98*64
    unsigned short* wbT = xp + BATCH * PADW * PADW * 64;   // 147456

    hipLaunchKernelGGL(prep_kernel, dim3(BATCH * PADW + 36), dim3(256), 0, stream,
                       x, wq, wk, wv, xp, wbT);
    hipLaunchKernelGGL(conv_mfma, dim3(384, 2), dim3(256), 0, stream,
                       xp, wbT, bq, bk, bv, Qb, Kb, Vb);
    hipLaunchKernelGGL(natt_mfma, dim3(1152), dim3(256), 0, stream,
                       Qb, Kb, Vb, (float*)d_out);
}

// Round 6
// 59.955 us; speedup vs baseline: 1.2020x; 1.2020x over previous
//
#include <hip/hip_runtime.h>
#include <math.h>

#define HWDIM 96
#define NPIX (HWDIM*HWDIM)     // 9216
#define BATCH 2
#define CIN 64
#define CCAT 128
#define PADW 98                // 96 + 2 halo

typedef __attribute__((ext_vector_type(8))) short bf16x8;
typedef __attribute__((ext_vector_type(4))) float f32x4;

__device__ __forceinline__ unsigned short f2bf(float f) {
    unsigned u = __builtin_bit_cast(unsigned, f);
    unsigned r = (u + 0x7FFFu + ((u >> 16) & 1u)) >> 16;
    return (unsigned short)r;
}

// ---------------------------------------------------------------------------
// Kernel A: prep = pad (blocks 0..195) + weight transpose (blocks 196..231)
// ---------------------------------------------------------------------------
__global__ __launch_bounds__(256) void prep_kernel(
        const float* __restrict__ x,
        const float* __restrict__ wq, const float* __restrict__ wk,
        const float* __restrict__ wv,
        unsigned short* __restrict__ xp, unsigned short* __restrict__ wbT) {
    int bid = blockIdx.x;
    int tid = threadIdx.x;
    if (bid < BATCH * PADW) {
        __shared__ float xls[64][97];
        int b  = bid / PADW;
        int hp = bid % PADW;
        bool interior = (hp >= 1 && hp <= HWDIM);
        if (interior) {
            int h = hp - 1;
            for (int idx = tid; idx < 64 * HWDIM; idx += 256) {
                int ci = idx / HWDIM;
                int w  = idx % HWDIM;
                xls[ci][w] = x[((b * CIN + ci) * HWDIM + h) * HWDIM + w];
            }
        }
        __syncthreads();
        for (int idx = tid; idx < PADW * 64; idx += 256) {
            int wp = idx / 64;
            int ci = idx % 64;
            float v = 0.f;
            if (interior && wp >= 1 && wp <= HWDIM) v = xls[ci][wp - 1];
            xp[((b * PADW + hp) * PADW + wp) * 64 + ci] = f2bf(v);
        }
    } else {
        int base = (bid - BATCH * PADW) * 4096;
        #pragma unroll
        for (int e = 0; e < 16; ++e) {
            int idx = base + e * 256 + tid;      // < 147456
            int t   = idx / (256 * 64);
            int rem = idx % (256 * 64);
            int co  = rem / 64;
            int ci  = rem % 64;
            float val;
            if (co < 64)        val = wq[(co * 64 + ci) * 9 + t];
            else if (co < 128)  val = wk[((co - 64) * 64 + ci) * 9 + t];
            else                val = wv[((co - 128) * 64 + ci) * 9 + t];
            wbT[(t * 256 + co) * 64 + ci] = f2bf(val);
        }
    }
}

// ---------------------------------------------------------------------------
// Kernel B: conv, tap-decomposed implicit GEMM, bf16 MFMA 16x16x32.
// grid = (384, 2): x -> (b, h, half-row of 48); y -> co chunk of 128.
// ---------------------------------------------------------------------------
__global__ __launch_bounds__(256) void conv_mfma(
        const unsigned short* __restrict__ xp,
        const unsigned short* __restrict__ wbT,
        const float* __restrict__ bq, const float* __restrict__ bk,
        const float* __restrict__ bv,
        unsigned short* __restrict__ Qb, unsigned short* __restrict__ Kb,
        unsigned short* __restrict__ Vb) {
    __shared__ unsigned short xs[3 * 50 * 72];   // 21600 B
    int bx   = blockIdx.x;
    int b    = bx / 192;
    int hh   = bx % 192;
    int h    = hh >> 1;
    int w0   = (hh & 1) * 48;
    int co0  = blockIdx.y * 128;
    int tid  = threadIdx.x;

    for (int i = tid; i < 1200; i += 256) {
        int r    = i / 400;
        int rem  = i % 400;
        int wp50 = rem >> 3;
        int c8   = rem & 7;
        const uint4* src = (const uint4*)&xp[(((b * PADW) + h + r) * PADW + w0 + wp50) * 64 + c8 * 8];
        *(uint4*)&xs[(r * 50 + wp50) * 72 + c8 * 8] = *src;
    }
    __syncthreads();

    int lane = tid & 63;
    int wv   = tid >> 6;
    int lw   = lane & 15;
    int ksub = (lane >> 4) * 8;
    int co_t = co0 + wv * 32;

    f32x4 acc[3][2];
    #pragma unroll
    for (int m = 0; m < 3; ++m)
        #pragma unroll
        for (int n = 0; n < 2; ++n) acc[m][n] = (f32x4){0.f, 0.f, 0.f, 0.f};

    #pragma unroll
    for (int t = 0; t < 9; ++t) {
        int kh = t / 3, kw = t % 3;
        #pragma unroll
        for (int half = 0; half < 2; ++half) {
            const unsigned short* ap = xs + (kh * 50 + lw + kw) * 72 + half * 32 + ksub;
            bf16x8 A0 = *(const bf16x8*)(ap);
            bf16x8 A1 = *(const bf16x8*)(ap + 16 * 72);
            bf16x8 A2 = *(const bf16x8*)(ap + 32 * 72);
            const unsigned short* bp = wbT + ((t * 256 + co_t + lw) * 64) + half * 32 + ksub;
            bf16x8 B0 = *(const bf16x8*)(bp);
            bf16x8 B1 = *(const bf16x8*)(bp + 16 * 64);
            acc[0][0] = __builtin_amdgcn_mfma_f32_16x16x32_bf16(A0, B0, acc[0][0], 0, 0, 0);
            acc[0][1] = __builtin_amdgcn_mfma_f32_16x16x32_bf16(A0, B1, acc[0][1], 0, 0, 0);
            acc[1][0] = __builtin_amdgcn_mfma_f32_16x16x32_bf16(A1, B0, acc[1][0], 0, 0, 0);
            acc[1][1] = __builtin_amdgcn_mfma_f32_16x16x32_bf16(A1, B1, acc[1][1], 0, 0, 0);
            acc[2][0] = __builtin_amdgcn_mfma_f32_16x16x32_bf16(A2, B0, acc[2][0], 0, 0, 0);
            acc[2][1] = __builtin_amdgcn_mfma_f32_16x16x32_bf16(A2, B1, acc[2][1], 0, 0, 0);
        }
    }

    #pragma unroll
    for (int n = 0; n < 2; ++n) {
        int cg   = co_t + n * 16;
        int co_f = cg + lw;
        #pragma unroll
        for (int m = 0; m < 3; ++m) {
            int wb = w0 + m * 16 + ((lane >> 4) << 2);
            if (cg < 64) {
                float bval = bq[co_f];
                #pragma unroll
                for (int r = 0; r < 4; ++r) {
                    int pix = b * NPIX + h * HWDIM + wb + r;
                    Qb[pix * CCAT + co_f] = f2bf(acc[m][n][r] + bval);
                }
            } else if (cg < 128) {
                int ch = co_f - 64;
                float bval = bk[ch];
                #pragma unroll
                for (int r = 0; r < 4; ++r) {
                    int pix = b * NPIX + h * HWDIM + wb + r;
                    Kb[pix * CCAT + ch] = f2bf(acc[m][n][r] + bval);
                }
            } else {
                int ch = co_f - 128;
                float bval = bv[ch];
                #pragma unroll
                for (int r = 0; r < 4; ++r) {
                    int pix = b * NPIX + h * HWDIM + wb + r;
                    Vb[pix * CCAT + ch] = f2bf(acc[m][n][r] + bval);
                }
            }
        }
    }

    if (blockIdx.y == 0) {
        for (int i = tid; i < 48 * 64; i += 256) {
            int c  = i & 63;
            int pl = i >> 6;
            int w  = w0 + pl;
            int pos = (c < 32) ? h : w;
            int j   = c & 15;
            float f   = exp2f(-(float)j * 0.83048202372184059f);
            float ang = (float)pos * f;
            float val = ((c & 16) == 0) ? sinf(ang) : cosf(ang);
            unsigned short bvv = f2bf(val);
            int pix = b * NPIX + h * HWDIM + w;
            Qb[pix * CCAT + 64 + c] = bvv;
            Kb[pix * CCAT + 64 + c] = bvv;
        }
    }
}

// ---------------------------------------------------------------------------
// Kernel C: neighborhood attention, fully MFMA.
// Vt staging: static-j unrolled extraction (no runtime reg indexing) +
// XOR column swizzle col' = col ^ ((row>>3 & 7)<<3); PV read undoes it.
// ---------------------------------------------------------------------------
#define KPAD 136   // bf16 row pad (272 B, 16B-aligned)
#define LGP  114   // f32 logit row stride; MUST be >= 112

__global__ __launch_bounds__(256) void natt_mfma(
        const unsigned short* __restrict__ Qb,
        const unsigned short* __restrict__ Kb,
        const unsigned short* __restrict__ Vb,
        float* __restrict__ out) {
    __shared__ unsigned short Ks[112 * KPAD];   // 30464 B
    __shared__ unsigned short Vt[128 * KPAD];   // 34816 B  Vt[ch][nbr^swz]
    __shared__ unsigned short Qs[16 * KPAD];    //  4352 B
    __shared__ unsigned short Pb[16 * KPAD];    //  4352 B  Pb[q][nbr]
    __shared__ float Lg[16 * LGP];              //  7296 B

    int bid = blockIdx.x;
    int tw = bid % 12;
    int th = (bid / 12) % 12;
    int gw = (bid / 144) & 1;
    int gh = (bid / 288) & 1;
    int b  = bid / 576;
    int rh0 = th * 4, rw0 = tw * 4;
    int base_h = min(max(rh0 - 3, 0), 41);
    int base_w = min(max(rw0 - 3, 0), 41);
    int tid = threadIdx.x;

    // zero ALL of Vt (contiguous, conflict-free): 17408 shorts = 2176 uint4
    for (int i = tid; i < 2176; i += 256)
        *(uint4*)(Vt + i * 8) = (uint4){0, 0, 0, 0};
    __syncthreads();

    // ---- stage K (row-major) + Q ----
    for (int c = tid; c < 1856; c += 256) {
        if (c < 1600) {
            int px = c >> 4, c8 = c & 15;
            int ih = px / 10, iw = px - ih * 10;
            int nh  = gh + 2 * min(base_h + ih, 47);
            int nw2 = gw + 2 * min(base_w + iw, 47);
            int gp  = b * NPIX + nh * HWDIM + nw2;
            uint4 v = *(const uint4*)(Kb + gp * CCAT + c8 * 8);
            *(uint4*)(Ks + px * KPAD + c8 * 8) = v;
        } else {
            int cc = c - 1600;
            int q  = cc >> 4, c8 = cc & 15;
            int qi = q >> 2, qj = q & 3;
            int hh = gh + 2 * (rh0 + qi);
            int ww = gw + 2 * (rw0 + qj);
            int gp = b * NPIX + hh * HWDIM + ww;
            uint4 v = *(const uint4*)(Qb + gp * CCAT + c8 * 8);
            *(uint4*)(Qs + q * KPAD + c8 * 8) = v;
        }
    }

    // ---- stage V transposed: row = ch, col = px ^ ((c8&7)<<3) ----
    for (int c = tid; c < 1600; c += 256) {
        int px = c >> 4, c8 = c & 15;
        int ih = px / 10, iw = px - ih * 10;
        int nh  = gh + 2 * min(base_h + ih, 47);
        int nw2 = gw + 2 * min(base_w + iw, 47);
        int gp  = b * NPIX + nh * HWDIM + nw2;
        uint4 v = *(const uint4*)(Vb + gp * CCAT + c8 * 8);
        int colx = px ^ ((c8 & 7) << 3);
        unsigned short* vp = Vt + (c8 * 8) * KPAD + colx;
        vp[0 * KPAD] = (unsigned short)(v.x & 0xFFFF);
        vp[1 * KPAD] = (unsigned short)(v.x >> 16);
        vp[2 * KPAD] = (unsigned short)(v.y & 0xFFFF);
        vp[3 * KPAD] = (unsigned short)(v.y >> 16);
        vp[4 * KPAD] = (unsigned short)(v.z & 0xFFFF);
        vp[5 * KPAD] = (unsigned short)(v.z >> 16);
        vp[6 * KPAD] = (unsigned short)(v.w & 0xFFFF);
        vp[7 * KPAD] = (unsigned short)(v.w >> 16);
    }
    __syncthreads();

    // ---- QK^T MFMA ----
    int lane = tid & 63;
    int wv   = tid >> 6;
    int lw   = lane & 15;
    int ks8  = (lane >> 4) * 8;
    const float scale = 0.08838834764831845f;

    #pragma unroll
    for (int tt = 0; tt < 2; ++tt) {
        int tile = wv + tt * 4;
        if (tile < 7) {
            f32x4 acc = (f32x4){0.f, 0.f, 0.f, 0.f};
            #pragma unroll
            for (int kk = 0; kk < 4; ++kk) {
                bf16x8 A  = *(const bf16x8*)(Qs + lw * KPAD + kk * 32 + ks8);
                bf16x8 Bf = *(const bf16x8*)(Ks + (tile * 16 + lw) * KPAD + kk * 32 + ks8);
                acc = __builtin_amdgcn_mfma_f32_16x16x32_bf16(A, Bf, acc, 0, 0, 0);
            }
            #pragma unroll
            for (int r = 0; r < 4; ++r) {
                int m = (lane >> 4) * 4 + r;
                Lg[m * LGP + tile * 16 + lw] = acc[r] * scale;
            }
        }
    }
    __syncthreads();

    // ---- softmax (16 threads per query) -> Pb bf16 ----
    int q   = tid >> 4, k16 = tid & 15;
    {
        int qi  = q >> 2, qj = q & 3;
        int rh  = rh0 + qi, rw = rw0 + qj;
        int oh  = min(max(rh - 3, 0), 41) - base_h;
        int ow  = min(max(rw - 3, 0), 41) - base_w;

        float ev[4];
        int   en[4];
        float mx = -1e30f;
        #pragma unroll
        for (int u = 0; u < 4; ++u) {
            int idx = k16 + u * 16;
            if (idx < 49) {
                int i = idx / 7, j = idx - i * 7;
                int n = (oh + i) * 10 + ow + j;
                en[u] = n;
                float l = Lg[q * LGP + n];
                ev[u] = l;
                mx = fmaxf(mx, l);
            } else { en[u] = -1; ev[u] = 0.f; }
        }
        #pragma unroll
        for (int off = 8; off > 0; off >>= 1) mx = fmaxf(mx, __shfl_xor(mx, off));
        float s = 0.f;
        #pragma unroll
        for (int u = 0; u < 4; ++u)
            if (en[u] >= 0) { ev[u] = __expf(ev[u] - mx); s += ev[u]; }
        #pragma unroll
        for (int off = 8; off > 0; off >>= 1) s += __shfl_xor(s, off);
        float rs = 1.0f / s;
        *(uint4*)(Pb + q * KPAD + k16 * 8) = (uint4){0, 0, 0, 0};
        #pragma unroll
        for (int u = 0; u < 4; ++u)
            if (en[u] >= 0) Pb[q * KPAD + en[u]] = f2bf(ev[u] * rs);
    }
    __syncthreads();

    // ---- PV MFMA: wave handles ch-tiles 2wv, 2wv+1 ----
    bf16x8 A4[4];
    #pragma unroll
    for (int kk = 0; kk < 4; ++kk)
        A4[kk] = *(const bf16x8*)(Pb + lw * KPAD + kk * 32 + ks8);

    #pragma unroll
    for (int tt = 0; tt < 2; ++tt) {
        int tile = wv * 2 + tt;
        int row  = tile * 16 + lw;
        int sw   = ((row >> 3) & 7) << 3;
        const unsigned short* vrow = Vt + row * KPAD;
        f32x4 acc = (f32x4){0.f, 0.f, 0.f, 0.f};
        #pragma unroll
        for (int kk = 0; kk < 4; ++kk) {
            bf16x8 Bf = *(const bf16x8*)(vrow + ((kk * 32 + ks8) ^ sw));
            acc = __builtin_amdgcn_mfma_f32_16x16x32_bf16(A4[kk], Bf, acc, 0, 0, 0);
        }
        int ch = row;
        #pragma unroll
        for (int r = 0; r < 4; ++r) {
            int qq = (lane >> 4) * 4 + r;
            int qi = qq >> 2, qj = qq & 3;
            int gp = b * NPIX + (gh + 2 * (rh0 + qi)) * HWDIM + (gw + 2 * (rw0 + qj));
            out[gp * CCAT + ch] = acc[r];
        }
    }
}

// ---------------------------------------------------------------------------
extern "C" void kernel_launch(void* const* d_in, const int* in_sizes, int n_in,
                              void* d_out, int out_size, void* d_ws, size_t ws_size,
                              hipStream_t stream) {
    const float* x  = (const float*)d_in[0];
    const float* wq = (const float*)d_in[1];
    const float* bq = (const float*)d_in[2];
    const float* wk = (const float*)d_in[3];
    const float* bk = (const float*)d_in[4];
    const float* wv = (const float*)d_in[5];
    const float* bv = (const float*)d_in[6];

    unsigned short* ws = (unsigned short*)d_ws;
    unsigned short* Qb  = ws;                              // 2359296 bf16
    unsigned short* Kb  = Qb + BATCH * NPIX * CCAT;
    unsigned short* Vb  = Kb + BATCH * NPIX * CCAT;
    unsigned short* xp  = Vb + BATCH * NPIX * CCAT;        // 2*98*98*64
    unsigned short* wbT = xp + BATCH * PADW * PADW * 64;   // 147456

    hipLaunchKernelGGL(prep_kernel, dim3(BATCH * PADW + 36), dim3(256), 0, stream,
                       x, wq, wk, wv, xp, wbT);
    hipLaunchKernelGGL(conv_mfma, dim3(384, 2), dim3(256), 0, stream,
                       xp, wbT, bq, bk, bv, Qb, Kb, Vb);
    hipLaunchKernelGGL(natt_mfma, dim3(1152), dim3(256), 0, stream,
                       Qb, Kb, Vb, (float*)d_out);
}

// Round 7
// 57.271 us; speedup vs baseline: 1.2584x; 1.0469x over previous
//
#include <hip/hip_runtime.h>
#include <math.h>

#define HWDIM 96
#define NPIX (HWDIM*HWDIM)     // 9216
#define BATCH 2
#define CIN 64
#define CCAT 128
#define PADW 98                // 96 + 2 halo

typedef __attribute__((ext_vector_type(8))) short bf16x8;
typedef __attribute__((ext_vector_type(4))) float f32x4;

__device__ __forceinline__ unsigned short f2bf(float f) {
    unsigned u = __builtin_bit_cast(unsigned, f);
    unsigned r = (u + 0x7FFFu + ((u >> 16) & 1u)) >> 16;
    return (unsigned short)r;
}

// ---------------------------------------------------------------------------
// Kernel A: prep = pad (blocks 0..195) + weight transpose (blocks 196..231)
// ---------------------------------------------------------------------------
__global__ __launch_bounds__(256) void prep_kernel(
        const float* __restrict__ x,
        const float* __restrict__ wq, const float* __restrict__ wk,
        const float* __restrict__ wv,
        unsigned short* __restrict__ xp, unsigned short* __restrict__ wbT) {
    int bid = blockIdx.x;
    int tid = threadIdx.x;
    if (bid < BATCH * PADW) {
        __shared__ float xls[64][97];
        int b  = bid / PADW;
        int hp = bid % PADW;
        bool interior = (hp >= 1 && hp <= HWDIM);
        if (interior) {
            int h = hp - 1;
            for (int idx = tid; idx < 64 * HWDIM; idx += 256) {
                int ci = idx / HWDIM;
                int w  = idx % HWDIM;
                xls[ci][w] = x[((b * CIN + ci) * HWDIM + h) * HWDIM + w];
            }
        }
        __syncthreads();
        for (int idx = tid; idx < PADW * 64; idx += 256) {
            int wp = idx / 64;
            int ci = idx % 64;
            float v = 0.f;
            if (interior && wp >= 1 && wp <= HWDIM) v = xls[ci][wp - 1];
            xp[((b * PADW + hp) * PADW + wp) * 64 + ci] = f2bf(v);
        }
    } else {
        int base = (bid - BATCH * PADW) * 4096;
        #pragma unroll
        for (int e = 0; e < 16; ++e) {
            int idx = base + e * 256 + tid;      // < 147456
            int t   = idx / (256 * 64);
            int rem = idx % (256 * 64);
            int co  = rem / 64;
            int ci  = rem % 64;
            float val;
            if (co < 64)        val = wq[(co * 64 + ci) * 9 + t];
            else if (co < 128)  val = wk[((co - 64) * 64 + ci) * 9 + t];
            else                val = wv[((co - 128) * 64 + ci) * 9 + t];
            wbT[(t * 256 + co) * 64 + ci] = f2bf(val);
        }
    }
}

// ---------------------------------------------------------------------------
// Kernel B: conv, tap-decomposed implicit GEMM, bf16 MFMA 16x16x32.
// grid = (384, 2). Epilogue: LDS-bounce (reuse xs) -> coalesced b128 stores.
// ---------------------------------------------------------------------------
__global__ __launch_bounds__(256) void conv_mfma(
        const unsigned short* __restrict__ xp,
        const unsigned short* __restrict__ wbT,
        const float* __restrict__ bq, const float* __restrict__ bk,
        const float* __restrict__ bv,
        unsigned short* __restrict__ Qb, unsigned short* __restrict__ Kb,
        unsigned short* __restrict__ Vb) {
    __shared__ unsigned short xs[3 * 50 * 72];   // 21600 B (also reused as [48][136])
    int bx   = blockIdx.x;
    int b    = bx / 192;
    int hh   = bx % 192;
    int h    = hh >> 1;
    int w0   = (hh & 1) * 48;
    int co0  = blockIdx.y * 128;
    int tid  = threadIdx.x;

    for (int i = tid; i < 1200; i += 256) {
        int r    = i / 400;
        int rem  = i % 400;
        int wp50 = rem >> 3;
        int c8   = rem & 7;
        const uint4* src = (const uint4*)&xp[(((b * PADW) + h + r) * PADW + w0 + wp50) * 64 + c8 * 8];
        *(uint4*)&xs[(r * 50 + wp50) * 72 + c8 * 8] = *src;
    }
    __syncthreads();

    int lane = tid & 63;
    int wv   = tid >> 6;
    int lw   = lane & 15;
    int ksub = (lane >> 4) * 8;
    int co_t = co0 + wv * 32;

    f32x4 acc[3][2];
    #pragma unroll
    for (int m = 0; m < 3; ++m)
        #pragma unroll
        for (int n = 0; n < 2; ++n) acc[m][n] = (f32x4){0.f, 0.f, 0.f, 0.f};

    #pragma unroll
    for (int t = 0; t < 9; ++t) {
        int kh = t / 3, kw = t % 3;
        #pragma unroll
        for (int half = 0; half < 2; ++half) {
            const unsigned short* ap = xs + (kh * 50 + lw + kw) * 72 + half * 32 + ksub;
            bf16x8 A0 = *(const bf16x8*)(ap);
            bf16x8 A1 = *(const bf16x8*)(ap + 16 * 72);
            bf16x8 A2 = *(const bf16x8*)(ap + 32 * 72);
            const unsigned short* bp = wbT + ((t * 256 + co_t + lw) * 64) + half * 32 + ksub;
            bf16x8 B0 = *(const bf16x8*)(bp);
            bf16x8 B1 = *(const bf16x8*)(bp + 16 * 64);
            acc[0][0] = __builtin_amdgcn_mfma_f32_16x16x32_bf16(A0, B0, acc[0][0], 0, 0, 0);
            acc[0][1] = __builtin_amdgcn_mfma_f32_16x16x32_bf16(A0, B1, acc[0][1], 0, 0, 0);
            acc[1][0] = __builtin_amdgcn_mfma_f32_16x16x32_bf16(A1, B0, acc[1][0], 0, 0, 0);
            acc[1][1] = __builtin_amdgcn_mfma_f32_16x16x32_bf16(A1, B1, acc[1][1], 0, 0, 0);
            acc[2][0] = __builtin_amdgcn_mfma_f32_16x16x32_bf16(A2, B0, acc[2][0], 0, 0, 0);
            acc[2][1] = __builtin_amdgcn_mfma_f32_16x16x32_bf16(A2, B1, acc[2][1], 0, 0, 0);
        }
    }

    // ---- epilogue: bias + f2bf into LDS bounce [48 px][136], then b128 stores
    __syncthreads();                 // xs reads complete; reuse as xs2
    unsigned short* xs2 = xs;        // [48][136], rows 16B-aligned
    #pragma unroll
    for (int n = 0; n < 2; ++n) {
        int co_f = co_t + n * 16 + lw;
        float bval;
        if (co_f < 64)       bval = bq[co_f];
        else if (co_f < 128) bval = bk[co_f - 64];
        else                 bval = bv[co_f - 128];
        int chl = wv * 32 + n * 16 + lw;   // local ch 0..127
        #pragma unroll
        for (int m = 0; m < 3; ++m) {
            int px = m * 16 + ((lane >> 4) << 2);
            #pragma unroll
            for (int r = 0; r < 4; ++r)
                xs2[(px + r) * 136 + chl] = f2bf(acc[m][n][r] + bval);
        }
    }
    __syncthreads();

    // coalesced stores: 768 x 16B chunks, 3 per thread
    for (int i = tid; i < 768; i += 256) {
        int px  = i >> 4;
        int seg = i & 15;
        uint4 v = *(uint4*)&xs2[px * 136 + seg * 8];
        int pix = b * NPIX + h * HWDIM + w0 + px;
        int chl = seg * 8;
        if (co0 == 0) {
            if (chl < 64) *(uint4*)&Qb[pix * CCAT + chl]        = v;
            else          *(uint4*)&Kb[pix * CCAT + (chl - 64)] = v;
        } else {
            *(uint4*)&Vb[pix * CCAT + chl] = v;
        }
    }

    // positional encoding (ch 64..127 of Qb and Kb) by y==0 blocks
    if (blockIdx.y == 0) {
        for (int i = tid; i < 48 * 64; i += 256) {
            int c  = i & 63;
            int pl = i >> 6;
            int w  = w0 + pl;
            int pos = (c < 32) ? h : w;
            int j   = c & 15;
            float f   = exp2f(-(float)j * 0.83048202372184059f);
            float ang = (float)pos * f;
            float val = ((c & 16) == 0) ? sinf(ang) : cosf(ang);
            unsigned short bvv = f2bf(val);
            int pix = b * NPIX + h * HWDIM + w;
            Qb[pix * CCAT + 64 + c] = bvv;
            Kb[pix * CCAT + 64 + c] = bvv;
        }
    }
}

// ---------------------------------------------------------------------------
// Kernel C: neighborhood attention, fully MFMA.
// Vt staging: paired-px b32 transpose writes + XOR col swizzle; zero pass only
// covers cols 64..127 (cols 0..63 are always fully overwritten: px^swz bijects
// [0,64) onto itself). setprio(1) around MFMA clusters.
// ---------------------------------------------------------------------------
#define KPAD 136   // bf16 row pad (272 B, 16B-aligned)
#define LGP  114   // f32 logit row stride; MUST be >= 112

__global__ __launch_bounds__(256) void natt_mfma(
        const unsigned short* __restrict__ Qb,
        const unsigned short* __restrict__ Kb,
        const unsigned short* __restrict__ Vb,
        float* __restrict__ out) {
    __shared__ unsigned short Ks[112 * KPAD];   // 30464 B
    __shared__ unsigned short Vt[128 * KPAD];   // 34816 B  Vt[ch][nbr^swz]
    __shared__ unsigned short Qs[16 * KPAD];    //  4352 B
    __shared__ unsigned short Pb[16 * KPAD];    //  4352 B  Pb[q][nbr]
    __shared__ float Lg[16 * LGP];              //  7296 B

    int bid = blockIdx.x;
    int tw = bid % 12;
    int th = (bid / 12) % 12;
    int gw = (bid / 144) & 1;
    int gh = (bid / 288) & 1;
    int b  = bid / 576;
    int rh0 = th * 4, rw0 = tw * 4;
    int base_h = min(max(rh0 - 3, 0), 41);
    int base_w = min(max(rw0 - 3, 0), 41);
    int tid = threadIdx.x;

    // zero Vt cols 64..127 only (128 rows x 8 chunks of 16B) = 4 iters
    for (int i = tid; i < 1024; i += 256) {
        int row = i >> 3, sg = i & 7;
        *(uint4*)(Vt + row * KPAD + 64 + sg * 8) = (uint4){0, 0, 0, 0};
    }
    __syncthreads();

    // ---- stage K (row-major) + Q ----
    for (int c = tid; c < 1856; c += 256) {
        if (c < 1600) {
            int px = c >> 4, c8 = c & 15;
            int ih = px / 10, iw = px - ih * 10;
            int nh  = gh + 2 * min(base_h + ih, 47);
            int nw2 = gw + 2 * min(base_w + iw, 47);
            int gp  = b * NPIX + nh * HWDIM + nw2;
            uint4 v = *(const uint4*)(Kb + gp * CCAT + c8 * 8);
            *(uint4*)(Ks + px * KPAD + c8 * 8) = v;
        } else {
            int cc = c - 1600;
            int q  = cc >> 4, c8 = cc & 15;
            int qi = q >> 2, qj = q & 3;
            int hh = gh + 2 * (rh0 + qi);
            int ww = gw + 2 * (rw0 + qj);
            int gp = b * NPIX + hh * HWDIM + ww;
            uint4 v = *(const uint4*)(Qb + gp * CCAT + c8 * 8);
            *(uint4*)(Qs + q * KPAD + c8 * 8) = v;
        }
    }

    // ---- stage V transposed, paired px: row = ch, col = px ^ ((ch>>3&7)<<3)
    // task = (px-pair, c8): 50*16 = 800
    for (int c = tid; c < 800; c += 256) {
        int pp = c >> 4, c8 = c & 15;
        int px0 = pp * 2;
        int ih0 = px0 / 10, iw0 = px0 - ih0 * 10;
        int px1 = px0 + 1;
        int ih1 = px1 / 10, iw1 = px1 - ih1 * 10;
        int gp0 = b * NPIX + (gh + 2 * min(base_h + ih0, 47)) * HWDIM + (gw + 2 * min(base_w + iw0, 47));
        int gp1 = b * NPIX + (gh + 2 * min(base_h + ih1, 47)) * HWDIM + (gw + 2 * min(base_w + iw1, 47));
        uint4 v0 = *(const uint4*)(Vb + gp0 * CCAT + c8 * 8);
        uint4 v1 = *(const uint4*)(Vb + gp1 * CCAT + c8 * 8);
        int colx = px0 ^ ((c8 & 7) << 3);       // even; px1 -> colx+1
        unsigned short* vp = Vt + (c8 * 8) * KPAD + colx;
        *(unsigned*)(vp + 0 * KPAD) = (v0.x & 0xFFFFu) | (v1.x << 16);
        *(unsigned*)(vp + 1 * KPAD) = (v0.x >> 16)     | (v1.x & 0xFFFF0000u);
        *(unsigned*)(vp + 2 * KPAD) = (v0.y & 0xFFFFu) | (v1.y << 16);
        *(unsigned*)(vp + 3 * KPAD) = (v0.y >> 16)     | (v1.y & 0xFFFF0000u);
        *(unsigned*)(vp + 4 * KPAD) = (v0.z & 0xFFFFu) | (v1.z << 16);
        *(unsigned*)(vp + 5 * KPAD) = (v0.z >> 16)     | (v1.z & 0xFFFF0000u);
        *(unsigned*)(vp + 6 * KPAD) = (v0.w & 0xFFFFu) | (v1.w << 16);
        *(unsigned*)(vp + 7 * KPAD) = (v0.w >> 16)     | (v1.w & 0xFFFF0000u);
    }
    __syncthreads();

    // ---- QK^T MFMA ----
    int lane = tid & 63;
    int wv   = tid >> 6;
    int lw   = lane & 15;
    int ks8  = (lane >> 4) * 8;
    const float scale = 0.08838834764831845f;

    __builtin_amdgcn_s_setprio(1);
    #pragma unroll
    for (int tt = 0; tt < 2; ++tt) {
        int tile = wv + tt * 4;
        if (tile < 7) {
            f32x4 acc = (f32x4){0.f, 0.f, 0.f, 0.f};
            #pragma unroll
            for (int kk = 0; kk < 4; ++kk) {
                bf16x8 A  = *(const bf16x8*)(Qs + lw * KPAD + kk * 32 + ks8);
                bf16x8 Bf = *(const bf16x8*)(Ks + (tile * 16 + lw) * KPAD + kk * 32 + ks8);
                acc = __builtin_amdgcn_mfma_f32_16x16x32_bf16(A, Bf, acc, 0, 0, 0);
            }
            #pragma unroll
            for (int r = 0; r < 4; ++r) {
                int m = (lane >> 4) * 4 + r;
                Lg[m * LGP + tile * 16 + lw] = acc[r] * scale;
            }
        }
    }
    __builtin_amdgcn_s_setprio(0);
    __syncthreads();

    // ---- softmax (16 threads per query) -> Pb bf16 ----
    int q   = tid >> 4, k16 = tid & 15;
    {
        int qi  = q >> 2, qj = q & 3;
        int rh  = rh0 + qi, rw = rw0 + qj;
        int oh  = min(max(rh - 3, 0), 41) - base_h;
        int ow  = min(max(rw - 3, 0), 41) - base_w;

        float ev[4];
        int   en[4];
        float mx = -1e30f;
        #pragma unroll
        for (int u = 0; u < 4; ++u) {
            int idx = k16 + u * 16;
            if (idx < 49) {
                int i = idx / 7, j = idx - i * 7;
                int n = (oh + i) * 10 + ow + j;
                en[u] = n;
                float l = Lg[q * LGP + n];
                ev[u] = l;
                mx = fmaxf(mx, l);
            } else { en[u] = -1; ev[u] = 0.f; }
        }
        #pragma unroll
        for (int off = 8; off > 0; off >>= 1) mx = fmaxf(mx, __shfl_xor(mx, off));
        float s = 0.f;
        #pragma unroll
        for (int u = 0; u < 4; ++u)
            if (en[u] >= 0) { ev[u] = __expf(ev[u] - mx); s += ev[u]; }
        #pragma unroll
        for (int off = 8; off > 0; off >>= 1) s += __shfl_xor(s, off);
        float rs = 1.0f / s;
        *(uint4*)(Pb + q * KPAD + k16 * 8) = (uint4){0, 0, 0, 0};
        #pragma unroll
        for (int u = 0; u < 4; ++u)
            if (en[u] >= 0) Pb[q * KPAD + en[u]] = f2bf(ev[u] * rs);
    }
    __syncthreads();

    // ---- PV MFMA: wave handles ch-tiles 2wv, 2wv+1 ----
    bf16x8 A4[4];
    #pragma unroll
    for (int kk = 0; kk < 4; ++kk)
        A4[kk] = *(const bf16x8*)(Pb + lw * KPAD + kk * 32 + ks8);

    __builtin_amdgcn_s_setprio(1);
    #pragma unroll
    for (int tt = 0; tt < 2; ++tt) {
        int tile = wv * 2 + tt;
        int row  = tile * 16 + lw;
        int sw   = ((row >> 3) & 7) << 3;
        const unsigned short* vrow = Vt + row * KPAD;
        f32x4 acc = (f32x4){0.f, 0.f, 0.f, 0.f};
        #pragma unroll
        for (int kk = 0; kk < 4; ++kk) {
            bf16x8 Bf = *(const bf16x8*)(vrow + ((kk * 32 + ks8) ^ sw));
            acc = __builtin_amdgcn_mfma_f32_16x16x32_bf16(A4[kk], Bf, acc, 0, 0, 0);
        }
        int ch = row;
        #pragma unroll
        for (int r = 0; r < 4; ++r) {
            int qq = (lane >> 4) * 4 + r;
            int qi = qq >> 2, qj = qq & 3;
            int gp = b * NPIX + (gh + 2 * (rh0 + qi)) * HWDIM + (gw + 2 * (rw0 + qj));
            out[gp * CCAT + ch] = acc[r];
        }
    }
    __builtin_amdgcn_s_setprio(0);
}

// ---------------------------------------------------------------------------
extern "C" void kernel_launch(void* const* d_in, const int* in_sizes, int n_in,
                              void* d_out, int out_size, void* d_ws, size_t ws_size,
                              hipStream_t stream) {
    const float* x  = (const float*)d_in[0];
    const float* wq = (const float*)d_in[1];
    const float* bq = (const float*)d_in[2];
    const float* wk = (const float*)d_in[3];
    const float* bk = (const float*)d_in[4];
    const float* wv = (const float*)d_in[5];
    const float* bv = (const float*)d_in[6];

    unsigned short* ws = (unsigned short*)d_ws;
    unsigned short* Qb  = ws;                              // 2359296 bf16
    unsigned short* Kb  = Qb + BATCH * NPIX * CCAT;
    unsigned short* Vb  = Kb + BATCH * NPIX * CCAT;
    unsigned short* xp  = Vb + BATCH * NPIX * CCAT;        // 2*98*98*64
    unsigned short* wbT = xp + BATCH * PADW * PADW * 64;   // 147456

    hipLaunchKernelGGL(prep_kernel, dim3(BATCH * PADW + 36), dim3(256), 0, stream,
                       x, wq, wk, wv, xp, wbT);
    hipLaunchKernelGGL(conv_mfma, dim3(384, 2), dim3(256), 0, stream,
                       xp, wbT, bq, bk, bv, Qb, Kb, Vb);
    hipLaunchKernelGGL(natt_mfma, dim3(1152), dim3(256), 0, stream,
                       Qb, Kb, Vb, (float*)d_out);
}